// Round 5
// baseline (288.706 us; speedup 1.0000x reference)
//
#include <hip/hip_runtime.h>

typedef __attribute__((ext_vector_type(8))) short short8;
typedef __attribute__((ext_vector_type(4))) float float4v;

__device__ __forceinline__ unsigned short f2bf(float f) {
    unsigned u = __float_as_uint(f);
    u = (u + 0x7FFFu + ((u >> 16) & 1u)) >> 16;
    return (unsigned short)u;
}

#define XSET 520   // 512 data + 8 pad ushorts per (g,ks) fragment set
#define CROW 68    // 64 px + 4 pad floats per staged C row
#define SMEM_BYTES 34816   // single aliased region: x frags / z frags / C staging

// ---------------------------------------------------------------------------
// Prepack: W1 [256x64], W2 [96x256] ([cin,cout]) -> bf16 MFMA A-frag order.
// A1: ((mt*8 + ks)*64 + lane)*8 + j   (mt 0..3,  ks 0..7)
// A2: ((mt*3 + ks)*64 + lane)*8 + j   (mt 0..15, ks 0..2)
// ---------------------------------------------------------------------------
__global__ void prepack(const float* __restrict__ W1_0, const float* __restrict__ W2_0,
                        const float* __restrict__ W1_1, const float* __restrict__ W2_1,
                        const float* __restrict__ W1_2, const float* __restrict__ W2_2,
                        unsigned short* __restrict__ ws) {
    int e = blockIdx.x * 256 + threadIdx.x;
    if (e >= 3 * 40960) return;
    int l = e / 40960, r = e % 40960;
    const float* W1 = (l == 0) ? W1_0 : (l == 1) ? W1_1 : W1_2;
    const float* W2 = (l == 0) ? W2_0 : (l == 1) ? W2_1 : W2_2;
    unsigned short* base = ws + l * 40960;
    if (r < 16384) {
        int j = r & 7, lane = (r >> 3) & 63, fs = r >> 9;
        int mt = fs >> 3, ks = fs & 7;
        int k = ks * 32 + (lane >> 4) * 8 + j;
        int m = mt * 16 + (lane & 15);
        base[r] = f2bf(W1[k * 64 + m]);
    } else {
        int r2 = r - 16384;
        int j = r2 & 7, lane = (r2 >> 3) & 63, fs = r2 >> 9;
        int mt = fs / 3, ks = fs - mt * 3;
        int k = ks * 32 + (lane >> 4) * 8 + j;
        int m = mt * 16 + (lane & 15);
        base[16384 + r2] = f2bf(W2[k * 256 + m]);
    }
}

// ---------------------------------------------------------------------------
// v8: the 64-px v6 tile structure (best measured: 60.4 us, 2.2 TB/s), but
// each block processes TWO adjacent 64-px tiles with cross-tile async
// staging: tile i+1's 16 global dwordx4 loads are issued immediately after
// tile i's x-fragments are consumed, so they stay in flight underneath
// tile i's MFMA1 / z / MFMA2 / C-store phases (T14 issue-early/write-late).
// Convoy -> pipeline: roughly doubles the per-block time spent with memory
// ops outstanding. LDS map unchanged (34816 B, x/z/C time-multiplexed).
// launch_bounds(256,3): prefetch regs (v[16] = 64 VGPR) live across the
// tile body push VGPR to ~150; 3 blocks/CU = 12 waves/CU = the measured
// BW-saturation occupancy of v3.
// ---------------------------------------------------------------------------
__device__ __forceinline__ void scatter_x(const float4v v[16], unsigned short* xs,
                                          int g, int n0, int ch_lo) {
#pragma unroll
    for (int i = 0; i < 16; ++i) {
        const int ch = i * 16 + ch_lo;
        const int ks = ch >> 5, qq = (ch >> 3) & 3, j = ch & 7;
        // +g*8 ushort (16 B) skew: breaks the mod-32-bank degeneracy.
        unsigned short* base = xs + (g * 8 + ks) * XSET + g * 8 + j;
#pragma unroll
        for (int e = 0; e < 4; ++e)
            base[(qq * 16 + n0 + e) * 8] = f2bf(v[i][e]);
    }
}

template<int HW>
__device__ __forceinline__ void tile_body(
    const short8 xf[8], const short8* __restrict__ A1f, const short8* __restrict__ A2f,
    const float* __restrict__ b1, const float* __restrict__ b2,
    float* __restrict__ o, int px0, unsigned short* __restrict__ xs,
    int lane, int w, int q, int n)
{
    unsigned short* zs = xs;               // z frags alias x region (barriered)

    // ---- stage 1: wave w -> px group g = w ----
    float4v acc1[4];
#pragma unroll
    for (int mt = 0; mt < 4; ++mt)
        acc1[mt] = *(const float4v*)(b1 + mt * 16 + q * 4);

#pragma unroll
    for (int ks = 0; ks < 8; ++ks)
#pragma unroll
        for (int mt = 0; mt < 4; ++mt)
            acc1[mt] = __builtin_amdgcn_mfma_f32_16x16x32_bf16(
                A1f[(mt * 8 + ks) * 64 + lane], xf[ks], acc1[mt], 0, 0, 0);

    // ---- z = [y, relu(y_hi)] -> frag-layout LDS (b64 packed) ----
    {
        unsigned short* zg = zs + w * 3 * XSET;
#pragma unroll
        for (int mt = 0; mt < 4; ++mt) {
            const int kb = mt * 16 + q * 4;
            unsigned long long pk =
                  (unsigned long long)f2bf(acc1[mt][0])
                | ((unsigned long long)f2bf(acc1[mt][1]) << 16)
                | ((unsigned long long)f2bf(acc1[mt][2]) << 32)
                | ((unsigned long long)f2bf(acc1[mt][3]) << 48);
            *(unsigned long long*)(zg + (kb >> 5) * XSET +
                (((kb >> 3) & 3) * 16 + n) * 8 + (kb & 7)) = pk;
            if (mt >= 2) {
                const int kr = kb + 32;    // relu copy at k = 64 + (ch-32)
                unsigned long long pr =
                      (unsigned long long)f2bf(fmaxf(acc1[mt][0], 0.f))
                    | ((unsigned long long)f2bf(fmaxf(acc1[mt][1], 0.f)) << 16)
                    | ((unsigned long long)f2bf(fmaxf(acc1[mt][2], 0.f)) << 32)
                    | ((unsigned long long)f2bf(fmaxf(acc1[mt][3], 0.f)) << 48);
                *(unsigned long long*)(zg + (kr >> 5) * XSET +
                    (((kr >> 3) & 3) * 16 + n) * 8 + (kr & 7)) = pr;
            }
        }
    }
    __syncthreads();

    // ---- stage 2: wave w -> out-ch 64w..64w+63, all 4 px groups ----
    float4v acc2[4][4];   // [mm][g]
#pragma unroll
    for (int mm = 0; mm < 4; ++mm) {
        float4v bb = *(const float4v*)(b2 + (w * 4 + mm) * 16 + q * 4);
#pragma unroll
        for (int g = 0; g < 4; ++g) acc2[mm][g] = bb;
    }

#pragma unroll
    for (int g = 0; g < 4; ++g) {
        short8 zf[3];
#pragma unroll
        for (int ks = 0; ks < 3; ++ks)
            zf[ks] = *(const short8*)(zs + (g * 3 + ks) * XSET + lane * 8);
#pragma unroll
        for (int ks = 0; ks < 3; ++ks)
#pragma unroll
            for (int mm = 0; mm < 4; ++mm)
                acc2[mm][g] = __builtin_amdgcn_mfma_f32_16x16x32_bf16(
                    A2f[((w * 4 + mm) * 3 + ks) * 64 + lane], zf[ks], acc2[mm][g], 0, 0, 0);
    }
    // all z reads done before C staging overwrites the region
    __syncthreads();

    // ---- store: C -> LDS (wave-private slot) -> px-major dwordx4 ----
    float* cw = (float*)xs + w * 32 * CROW;
#pragma unroll
    for (int p = 0; p < 2; ++p) {
#pragma unroll
        for (int mp = 0; mp < 2; ++mp) {
            const int mm = p * 2 + mp;
#pragma unroll
            for (int g = 0; g < 4; ++g)
#pragma unroll
                for (int r = 0; r < 4; ++r)
                    cw[(mp * 16 + q * 4 + r) * CROW + g * 16 + n] = acc2[mm][g][r];
        }
        // wave-private slot: DS ops from one wave execute in order; no barrier
        const int chs = lane >> 4;         // 0..3
        const int pp = lane & 15;
        float* op = o + (size_t)(w * 64 + p * 32 + chs) * HW + px0 + 4 * pp;
#pragma unroll
        for (int i = 0; i < 8; ++i) {
            float4v vv = *(const float4v*)(cw + (i * 4 + chs) * CROW + 4 * pp);
            *(float4v*)(op + (size_t)(i * 4) * HW) = vv;
        }
    }
}

template<int HW>
__device__ __forceinline__ void level3_pair(
    const float* __restrict__ x,           // this batch: [256][HW]
    const unsigned short* __restrict__ A1,
    const unsigned short* __restrict__ A2,
    const float* __restrict__ b1, const float* __restrict__ b2,
    float* __restrict__ o, int px0,        // tiles at px0, px0+64
    unsigned short* __restrict__ xs)
{
    const int t = (int)threadIdx.x;
    const int lane = t & 63, w = t >> 6;
    const int q = lane >> 4, n = lane & 15;
    const short8* A1f = (const short8*)A1;
    const short8* A2f = (const short8*)A2;

    const int ch_lo = t >> 4;              // 0..15
    const int pp = t & 15;                 // px = 4*pp + e
    const int g = pp >> 2;
    const int n0 = (pp & 3) * 4;
    const float* xp = x + (size_t)ch_lo * HW + px0 + 4 * pp;

    // ---- tile 0: load + scatter ----
    float4v v[16];
#pragma unroll
    for (int i = 0; i < 16; ++i)
        v[i] = *(const float4v*)(xp + (size_t)(i * 16) * HW);
    scatter_x(v, xs, g, n0, ch_lo);
    __syncthreads();

    short8 xf[8];
#pragma unroll
    for (int ks = 0; ks < 8; ++ks)
        xf[ks] = *(const short8*)(xs + (w * 8 + ks) * XSET + w * 8 + lane * 8);
    __syncthreads();   // all x frags consumed; region free for z/C

    // ---- issue tile 1 loads NOW: in flight under tile 0's entire body ----
#pragma unroll
    for (int i = 0; i < 16; ++i)
        v[i] = *(const float4v*)(xp + 64 + (size_t)(i * 16) * HW);

    tile_body<HW>(xf, A1f, A2f, b1, b2, o, px0, xs, lane, w, q, n);
    __syncthreads();   // all C-slot LDS reads done before tile-1 scatter

    // ---- tile 1: scatter (waits vmcnt here, deep in the pipeline) ----
    scatter_x(v, xs, g, n0, ch_lo);
    __syncthreads();
#pragma unroll
    for (int ks = 0; ks < 8; ++ks)
        xf[ks] = *(const short8*)(xs + (w * 8 + ks) * XSET + w * 8 + lane * 8);
    __syncthreads();

    tile_body<HW>(xf, A1f, A2f, b1, b2, o, px0 + 64, xs, lane, w, q, n);
}

__global__ __launch_bounds__(256, 3) void fused_v8(
    const float* __restrict__ x0, const float* __restrict__ x1, const float* __restrict__ x2,
    const float* __restrict__ b1_0, const float* __restrict__ b2_0,
    const float* __restrict__ b1_1, const float* __restrict__ b2_1,
    const float* __restrict__ b1_2, const float* __restrict__ b2_2,
    const unsigned short* __restrict__ wpk, float* __restrict__ out)
{
    __shared__ __align__(16) unsigned char smem[SMEM_BYTES];
    unsigned short* xs = (unsigned short*)smem;
    const int bi = (int)blockIdx.x;

    if (bi < 512) {                         // level 0: 4 batches x 128 pair-tiles
        int b = bi >> 7, px0 = (bi & 127) * 128;
        level3_pair<16384>(x0 + (size_t)b * 4194304, wpk, wpk + 16384, b1_0, b2_0,
                           out + (size_t)b * 4194304, px0, xs);
    } else if (bi < 640) {                  // level 1: 4 x 32 pair-tiles
        int r = bi - 512, b = r >> 5, px0 = (r & 31) * 128;
        level3_pair<4096>(x1 + (size_t)b * 1048576, wpk + 40960, wpk + 57344,
                          b1_1, b2_1, out + 16777216 + (size_t)b * 1048576, px0, xs);
    } else {                                // level 2: 4 x 8 pair-tiles
        int r = bi - 640, b = r >> 3, px0 = (r & 7) * 128;
        level3_pair<1024>(x2 + (size_t)b * 262144, wpk + 81920, wpk + 98304,
                          b1_2, b2_2, out + 20971520 + (size_t)b * 262144, px0, xs);
    }
}

extern "C" void kernel_launch(void* const* d_in, const int* in_sizes, int n_in,
                              void* d_out, int out_size, void* d_ws, size_t ws_size,
                              hipStream_t stream) {
    const float* x0   = (const float*)d_in[0];
    const float* x1   = (const float*)d_in[1];
    const float* x2   = (const float*)d_in[2];
    const float* W1_0 = (const float*)d_in[3];
    const float* b1_0 = (const float*)d_in[4];
    const float* W2_0 = (const float*)d_in[5];
    const float* b2_0 = (const float*)d_in[6];
    const float* W1_1 = (const float*)d_in[7];
    const float* b1_1 = (const float*)d_in[8];
    const float* W2_1 = (const float*)d_in[9];
    const float* b2_1 = (const float*)d_in[10];
    const float* W1_2 = (const float*)d_in[11];
    const float* b1_2 = (const float*)d_in[12];
    const float* W2_2 = (const float*)d_in[13];
    const float* b2_2 = (const float*)d_in[14];
    float* out = (float*)d_out;
    unsigned short* wpk = (unsigned short*)d_ws;   // needs 245760 B

    prepack<<<dim3(480), dim3(256), 0, stream>>>(W1_0, W2_0, W1_1, W2_1, W1_2, W2_2, wpk);
    fused_v8<<<dim3(672), dim3(256), 0, stream>>>(
        x0, x1, x2, b1_0, b2_0, b1_1, b2_1, b1_2, b2_2, wpk, out);
}

// Round 6
// 218.066 us; speedup vs baseline: 1.3239x; 1.3239x over previous
//
#include <hip/hip_runtime.h>

typedef __attribute__((ext_vector_type(8))) short short8;
typedef __attribute__((ext_vector_type(4))) float float4v;

__device__ __forceinline__ unsigned short f2bf(float f) {
    unsigned u = __float_as_uint(f);
    u = (u + 0x7FFFu + ((u >> 16) & 1u)) >> 16;
    return (unsigned short)u;
}

#define XSET 520   // 512 data + 8 pad ushorts per (g,ks) fragment set
#define CROW 68    // 64 px + 4 pad floats per staged C row
// LDS map (de-aliased so x-frags never collide with C staging):
//   [0, 33312)        X: x frags, 32 sets * 520 u16 + per-g skew
//   [33312, 50720)    Z: z frags (12480 B)  /  C staging (17408 B) -- aliased,
//                     separated by barriers (z reads done before C writes;
//                     C reads done before next tile's z writes)
#define X_BYTES 33312
#define SMEM_BYTES 50720   // 3 blocks/CU (<= 54613)

// ---------------------------------------------------------------------------
// Prepack: W1 [256x64], W2 [96x256] ([cin,cout]) -> bf16 MFMA A-frag order.
// A1: ((mt*8 + ks)*64 + lane)*8 + j   (mt 0..3,  ks 0..7)
// A2: ((mt*3 + ks)*64 + lane)*8 + j   (mt 0..15, ks 0..2)
// ---------------------------------------------------------------------------
__global__ void prepack(const float* __restrict__ W1_0, const float* __restrict__ W2_0,
                        const float* __restrict__ W1_1, const float* __restrict__ W2_1,
                        const float* __restrict__ W1_2, const float* __restrict__ W2_2,
                        unsigned short* __restrict__ ws) {
    int e = blockIdx.x * 256 + threadIdx.x;
    if (e >= 3 * 40960) return;
    int l = e / 40960, r = e % 40960;
    const float* W1 = (l == 0) ? W1_0 : (l == 1) ? W1_1 : W1_2;
    const float* W2 = (l == 0) ? W2_0 : (l == 1) ? W2_1 : W2_2;
    unsigned short* base = ws + l * 40960;
    if (r < 16384) {
        int j = r & 7, lane = (r >> 3) & 63, fs = r >> 9;
        int mt = fs >> 3, ks = fs & 7;
        int k = ks * 32 + (lane >> 4) * 8 + j;
        int m = mt * 16 + (lane & 15);
        base[r] = f2bf(W1[k * 64 + m]);
    } else {
        int r2 = r - 16384;
        int j = r2 & 7, lane = (r2 >> 3) & 63, fs = r2 >> 9;
        int mt = fs / 3, ks = fs - mt * 3;
        int k = ks * 32 + (lane >> 4) * 8 + j;
        int m = mt * 16 + (lane & 15);
        base[16384 + r2] = f2bf(W2[k * 256 + m]);
    }
}

// ---- helpers ---------------------------------------------------------------

template<int I0, int I1>
__device__ __forceinline__ void scatter_x(const float4v* v, unsigned short* xs,
                                          int g, int n0, int ch_lo) {
#pragma unroll
    for (int i = I0; i < I1; ++i) {
        const int ch = i * 16 + ch_lo;
        const int ks = ch >> 5, qq = (ch >> 3) & 3, j = ch & 7;
        // +g*8 ushort (16 B) skew breaks the mod-32-bank degeneracy.
        unsigned short* base = xs + (g * 8 + ks) * XSET + g * 8 + j;
#pragma unroll
        for (int e = 0; e < 4; ++e)
            base[(qq * 16 + n0 + e) * 8] = f2bf(v[i][e]);
    }
}

__device__ __forceinline__ void fragread(short8 xf[8], const unsigned short* xs,
                                         int w, int lane) {
#pragma unroll
    for (int ks = 0; ks < 8; ++ks)
        xf[ks] = *(const short8*)(xs + (w * 8 + ks) * XSET + w * 8 + lane * 8);
}

__device__ __forceinline__ void mfma1(float4v acc1[4], const short8 xf[8],
                                      const short8* __restrict__ A1f,
                                      const float* __restrict__ b1, int lane, int q) {
#pragma unroll
    for (int mt = 0; mt < 4; ++mt)
        acc1[mt] = *(const float4v*)(b1 + mt * 16 + q * 4);
#pragma unroll
    for (int ks = 0; ks < 8; ++ks)
#pragma unroll
        for (int mt = 0; mt < 4; ++mt)
            acc1[mt] = __builtin_amdgcn_mfma_f32_16x16x32_bf16(
                A1f[(mt * 8 + ks) * 64 + lane], xf[ks], acc1[mt], 0, 0, 0);
}

__device__ __forceinline__ void zwrite(const float4v acc1[4], unsigned short* zs,
                                       int w, int q, int n) {
    unsigned short* zg = zs + w * 3 * XSET;
#pragma unroll
    for (int mt = 0; mt < 4; ++mt) {
        const int kb = mt * 16 + q * 4;
        unsigned long long pk =
              (unsigned long long)f2bf(acc1[mt][0])
            | ((unsigned long long)f2bf(acc1[mt][1]) << 16)
            | ((unsigned long long)f2bf(acc1[mt][2]) << 32)
            | ((unsigned long long)f2bf(acc1[mt][3]) << 48);
        *(unsigned long long*)(zg + (kb >> 5) * XSET +
            (((kb >> 3) & 3) * 16 + n) * 8 + (kb & 7)) = pk;
        if (mt >= 2) {
            const int kr = kb + 32;        // relu copy at k = 64 + (ch-32)
            unsigned long long pr =
                  (unsigned long long)f2bf(fmaxf(acc1[mt][0], 0.f))
                | ((unsigned long long)f2bf(fmaxf(acc1[mt][1], 0.f)) << 16)
                | ((unsigned long long)f2bf(fmaxf(acc1[mt][2], 0.f)) << 32)
                | ((unsigned long long)f2bf(fmaxf(acc1[mt][3], 0.f)) << 48);
            *(unsigned long long*)(zg + (kr >> 5) * XSET +
                (((kr >> 3) & 3) * 16 + n) * 8 + (kr & 7)) = pr;
        }
    }
}

__device__ __forceinline__ void mfma2(float4v acc2[4][4], const unsigned short* zs,
                                      const short8* __restrict__ A2f,
                                      const float* __restrict__ b2,
                                      int lane, int w, int q) {
#pragma unroll
    for (int mm = 0; mm < 4; ++mm) {
        float4v bb = *(const float4v*)(b2 + (w * 4 + mm) * 16 + q * 4);
#pragma unroll
        for (int g = 0; g < 4; ++g) acc2[mm][g] = bb;
    }
#pragma unroll
    for (int g = 0; g < 4; ++g) {
        short8 zf[3];
#pragma unroll
        for (int ks = 0; ks < 3; ++ks)
            zf[ks] = *(const short8*)(zs + (g * 3 + ks) * XSET + lane * 8);
#pragma unroll
        for (int ks = 0; ks < 3; ++ks)
#pragma unroll
            for (int mm = 0; mm < 4; ++mm)
                acc2[mm][g] = __builtin_amdgcn_mfma_f32_16x16x32_bf16(
                    A2f[((w * 4 + mm) * 3 + ks) * 64 + lane], zf[ks], acc2[mm][g], 0, 0, 0);
    }
}

// C staging: 16-row wave-private slots (4352 B/wave), 4 passes of one mm each.
// Within a pass: wave writes rows -> reads rows -> global stores; DS ops of
// one wave execute in order, so no barrier (same discipline as v6's p-loop).
template<int HW>
__device__ __forceinline__ void cstore(const float4v acc2[4][4], float* cb,
                                       float* __restrict__ o, int px0,
                                       int lane, int w, int q, int n) {
    float* cww = cb + w * 16 * CROW;
    const int chs = lane >> 4, ppx = lane & 15;
#pragma unroll
    for (int mm = 0; mm < 4; ++mm) {
#pragma unroll
        for (int g = 0; g < 4; ++g)
#pragma unroll
            for (int r = 0; r < 4; ++r)
                cww[(q * 4 + r) * CROW + g * 16 + n] = acc2[mm][g][r];
        float* op = o + (size_t)(w * 64 + mm * 16 + chs) * HW + px0 + 4 * ppx;
#pragma unroll
        for (int i = 0; i < 4; ++i) {
            float4v vv = *(const float4v*)(cww + (i * 4 + chs) * CROW + 4 * ppx);
            *(float4v*)(op + (size_t)(i * 4) * HW) = vv;
        }
    }
}

// ---------------------------------------------------------------------------
// v9: two 64-px tiles per block, cross-tile pipeline with bounded register
// overlap. Tile-1 loads issue right after tile-0's frag-read barrier; the
// scatter happens in two 8-load halves (after zwrite, after MFMA2) so the
// prefetch never coexists with the full acc2 file (v8's spill: VGPR 84,
// FETCH/WRITE 3x). X region is never aliased, so scatter(t1) needs no wait
// on tile-0's store phase.
// ---------------------------------------------------------------------------
template<int HW>
__device__ __forceinline__ void level3_pair(
    const float* __restrict__ x,           // this batch: [256][HW]
    const unsigned short* __restrict__ A1,
    const unsigned short* __restrict__ A2,
    const float* __restrict__ b1, const float* __restrict__ b2,
    float* __restrict__ o, int px0,        // tiles at px0, px0+64
    unsigned char* __restrict__ smem)
{
    unsigned short* xs = (unsigned short*)smem;            // X frags
    unsigned short* zs = (unsigned short*)(smem + X_BYTES);// Z frags
    float*          cb = (float*)(smem + X_BYTES);         // C staging (alias Z)

    const int t = (int)threadIdx.x;
    const int lane = t & 63, w = t >> 6;
    const int q = lane >> 4, n = lane & 15;
    const short8* A1f = (const short8*)A1;
    const short8* A2f = (const short8*)A2;

    const int ch_lo = t >> 4;              // 0..15
    const int pp = t & 15;                 // px = 4*pp + e
    const int g = pp >> 2;
    const int n0 = (pp & 3) * 4;
    const float* xp = x + (size_t)ch_lo * HW + px0 + 4 * pp;

    // ---- prologue: tile 0 stage ----
    float4v v[16];
#pragma unroll
    for (int i = 0; i < 16; ++i)
        v[i] = *(const float4v*)(xp + (size_t)(i * 16) * HW);
    scatter_x<0, 16>(v, xs, g, n0, ch_lo);
    __syncthreads();                                   // (1) x frags visible
    short8 xf[8];
    fragread(xf, xs, w, lane);
    __syncthreads();                                   // (2) X free for refill

    // ---- tile 0 body, tile 1 prefetch in flight ----
#pragma unroll
    for (int i = 0; i < 16; ++i)
        v[i] = *(const float4v*)(xp + 64 + (size_t)(i * 16) * HW);
    __builtin_amdgcn_sched_barrier(0);     // pin load issue above the MFMAs

    float4v acc1[4];
    mfma1(acc1, xf, A1f, b1, lane, q);
    zwrite(acc1, zs, w, q, n);
    scatter_x<0, 8>(v, xs, g, n0, ch_lo);  // first half lands post-MFMA1
    __syncthreads();                                   // (3) z ready
    float4v acc2[4][4];
    mfma2(acc2, zs, A2f, b2, lane, w, q);
    scatter_x<8, 16>(v, xs, g, n0, ch_lo); // second half lands post-MFMA2
    __syncthreads();                                   // (4) z reads done; X(t1) ready
    fragread(xf, xs, w, lane);             // t1 frags
    cstore<HW>(acc2, cb, o, px0, lane, w, q, n);
    __syncthreads();                                   // (5) C reads done -> Z writable

    // ---- tile 1 body ----
    mfma1(acc1, xf, A1f, b1, lane, q);
    zwrite(acc1, zs, w, q, n);
    __syncthreads();                                   // (6) z ready
    mfma2(acc2, zs, A2f, b2, lane, w, q);
    __syncthreads();                                   // (7) z reads done
    cstore<HW>(acc2, cb, o, px0 + 64, lane, w, q, n);
}

__global__ __launch_bounds__(256, 3) void fused_v9(
    const float* __restrict__ x0, const float* __restrict__ x1, const float* __restrict__ x2,
    const float* __restrict__ b1_0, const float* __restrict__ b2_0,
    const float* __restrict__ b1_1, const float* __restrict__ b2_1,
    const float* __restrict__ b1_2, const float* __restrict__ b2_2,
    const unsigned short* __restrict__ wpk, float* __restrict__ out)
{
    __shared__ __align__(16) unsigned char smem[SMEM_BYTES];
    const int bi = (int)blockIdx.x;

    if (bi < 512) {                         // level 0: 4 batches x 128 pair-tiles
        int b = bi >> 7, px0 = (bi & 127) * 128;
        level3_pair<16384>(x0 + (size_t)b * 4194304, wpk, wpk + 16384, b1_0, b2_0,
                           out + (size_t)b * 4194304, px0, smem);
    } else if (bi < 640) {                  // level 1: 4 x 32 pair-tiles
        int r = bi - 512, b = r >> 5, px0 = (r & 31) * 128;
        level3_pair<4096>(x1 + (size_t)b * 1048576, wpk + 40960, wpk + 57344,
                          b1_1, b2_1, out + 16777216 + (size_t)b * 1048576, px0, smem);
    } else {                                // level 2: 4 x 8 pair-tiles
        int r = bi - 640, b = r >> 3, px0 = (r & 7) * 128;
        level3_pair<1024>(x2 + (size_t)b * 262144, wpk + 81920, wpk + 98304,
                          b1_2, b2_2, out + 20971520 + (size_t)b * 262144, px0, smem);
    }
}

extern "C" void kernel_launch(void* const* d_in, const int* in_sizes, int n_in,
                              void* d_out, int out_size, void* d_ws, size_t ws_size,
                              hipStream_t stream) {
    const float* x0   = (const float*)d_in[0];
    const float* x1   = (const float*)d_in[1];
    const float* x2   = (const float*)d_in[2];
    const float* W1_0 = (const float*)d_in[3];
    const float* b1_0 = (const float*)d_in[4];
    const float* W2_0 = (const float*)d_in[5];
    const float* b2_0 = (const float*)d_in[6];
    const float* W1_1 = (const float*)d_in[7];
    const float* b1_1 = (const float*)d_in[8];
    const float* W2_1 = (const float*)d_in[9];
    const float* b2_1 = (const float*)d_in[10];
    const float* W1_2 = (const float*)d_in[11];
    const float* b1_2 = (const float*)d_in[12];
    const float* W2_2 = (const float*)d_in[13];
    const float* b2_2 = (const float*)d_in[14];
    float* out = (float*)d_out;
    unsigned short* wpk = (unsigned short*)d_ws;   // needs 245760 B

    prepack<<<dim3(480), dim3(256), 0, stream>>>(W1_0, W2_0, W1_1, W2_1, W1_2, W2_2, wpk);
    fused_v9<<<dim3(672), dim3(256), 0, stream>>>(
        x0, x1, x2, b1_0, b2_0, b1_1, b2_1, b1_2, b2_2, wpk, out);
}